// Round 1
// baseline (186.067 us; speedup 1.0000x reference)
//
#include <hip/hip_runtime.h>
#include <hip/hip_bf16.h>
#include <cstdint>
#include <cstddef>

// ---- types ----
typedef __attribute__((ext_vector_type(8))) short short8;       // 8 bf16 (4 VGPR) MFMA frag
typedef __attribute__((ext_vector_type(4))) float floatx4;      // MFMA accumulator
typedef __attribute__((ext_vector_type(2))) unsigned int uintx2;     // 8B vector st

#define MFMA16(a, b, c) __builtin_amdgcn_mfma_f32_16x16x32_bf16((a), (b), (c), 0, 0, 0)
#define LOG2E 1.44269504088896340736f
#define EXP2(x) __builtin_amdgcn_exp2f(x)

__device__ __forceinline__ unsigned short f2bf(float f) {
  unsigned int u = __builtin_bit_cast(unsigned int, f);
  u += 0x7fffu + ((u >> 16) & 1u);          // RNE
  return (unsigned short)(u >> 16);
}

// packed bf16 pair via v_cvt_pk_bf16_f32 (RNE); memcpy avoids bit_cast restriction
__device__ __forceinline__ unsigned int pk2(float a, float b) {
  float2 f; f.x = a; f.y = b;
  __hip_bfloat162 h = __float22bfloat162_rn(f);
  unsigned int u;
  __builtin_memcpy(&u, &h, 4);
  return u;
}

typedef __attribute__((address_space(1))) void gvoid_t;
typedef __attribute__((address_space(3))) void svoid_t;
__device__ __forceinline__ void gload_lds16(const void* g, void* l) {
  // LDS dest = wave-uniform base + lane*16; global side is per-lane addresses.
  __builtin_amdgcn_global_load_lds((gvoid_t*)(uintptr_t)g, (svoid_t*)(uintptr_t)l, 16, 0, 0);
}

// ---------------- convert x: fp32 -> bf16 ----------------
__global__ void convert_x(const float* __restrict__ x, unsigned short* __restrict__ xb) {
  int i = (blockIdx.x * 256 + threadIdx.x) * 4;
  floatx4 v = *(const floatx4*)(x + i);
  uintx2 o;
  o[0] = pk2(v[0], v[1]);
  o[1] = pk2(v[2], v[3]);
  *(uintx2*)(xb + i) = o;
}

// ---------------- transpose weights -> bf16 N x K ----------------
__global__ void transpose_w(const float* __restrict__ Wq, const float* __restrict__ Wk,
                            const float* __restrict__ Wv, const float* __restrict__ Wo,
                            unsigned short* __restrict__ Wqkvt, unsigned short* __restrict__ Wot) {
  __shared__ float tile[32][33];
  int z = blockIdx.z;
  const float* W = (z == 0) ? Wq : (z == 1) ? Wk : (z == 2) ? Wv : Wo;
  unsigned short* out = (z == 3) ? Wot : (Wqkvt + (size_t)z * 1024 * 1024);
  int n0 = blockIdx.x * 32, k0 = blockIdx.y * 32;
  int tx = threadIdx.x, ty = threadIdx.y;            // block (32,8)
#pragma unroll
  for (int j = 0; j < 4; ++j)
    tile[ty + j * 8][tx] = W[(size_t)(k0 + ty + j * 8) * 1024 + n0 + tx];
  __syncthreads();
#pragma unroll
  for (int j = 0; j < 4; ++j)
    out[(size_t)(n0 + ty + j * 8) * 1024 + k0 + tx] = f2bf(tile[tx][ty + j * 8]);
}

// ---------------- GEMM core v4: 128x128 tile (m97 shape), BK=64, XOR-swizzled LDS ----------------
// 4 waves, each owns a 64x64 quadrant (acc[4][4] of 16x16). 32 KB LDS, 2-barrier loop.
#define GEMM_PROLOGUE()                                                        \
  __shared__ __align__(16) unsigned short As[128 * 64];                        \
  __shared__ __align__(16) unsigned short Bs[128 * 64];                        \
  const int tid = threadIdx.x;                                                 \
  const int lane = tid & 63;                                                   \
  const int wid = tid >> 6;                                                    \
  const int col = lane & 15;                                                   \
  const int quad = lane >> 4;                                                  \
  const int m0 = blockIdx.x * 128;                                             \
  const int n0 = blockIdx.y * 128;                                             \
  const int wm = wid >> 1;                                                     \
  const int wn = wid & 1;                                                      \
  floatx4 acc[4][4];                                                           \
  _Pragma("unroll") for (int i = 0; i < 4; ++i)                                \
      _Pragma("unroll") for (int j = 0; j < 4; ++j)                            \
          acc[i][j] = (floatx4)(0.f);                                          \
  _Pragma("unroll 1") for (int kt = 0; kt < 16; ++kt) {                        \
    __syncthreads();                                                           \
    _Pragma("unroll") for (int call = 0; call < 4; ++call) {                   \
      int c = call * 256 + tid;                                                \
      int r = c >> 3, ch = c & 7;                                              \
      gload_lds16(A + (size_t)(m0 + r) * 1024 + kt * 64 + ((ch ^ (r & 7)) * 8),\
                  As + (size_t)(call * 256 + wid * 64) * 8);                   \
      gload_lds16(Bt + (size_t)(n0 + r) * 1024 + kt * 64 + ((ch ^ (r & 7)) * 8),\
                  Bs + (size_t)(call * 256 + wid * 64) * 8);                   \
    }                                                                          \
    __syncthreads();                                                           \
    _Pragma("unroll") for (int ks = 0; ks < 2; ++ks) {                         \
      short8 af[4], bf[4];                                                     \
      _Pragma("unroll") for (int rt = 0; rt < 4; ++rt) {                       \
        int row = wm * 64 + rt * 16 + col;                                     \
        af[rt] = *(const short8*)&As[row * 64 + (((ks * 4 + quad) ^ (row & 7)) * 8)]; \
      }                                                                        \
      _Pragma("unroll") for (int ct = 0; ct < 4; ++ct) {                       \
        int row = wn * 64 + ct * 16 + col;                                     \
        bf[ct] = *(const short8*)&Bs[row * 64 + (((ks * 4 + quad) ^ (row & 7)) * 8)]; \
      }                                                                        \
      _Pragma("unroll") for (int rt = 0; rt < 4; ++rt)                         \
          _Pragma("unroll") for (int ct = 0; ct < 4; ++ct)                     \
              acc[rt][ct] = MFMA16(af[rt], bf[ct], acc[rt][ct]);               \
    }                                                                          \
  }

__global__ __launch_bounds__(256, 3)
void gemm_qkv(const unsigned short* __restrict__ A, const unsigned short* __restrict__ Bt,
              const float* __restrict__ bq, const float* __restrict__ bk,
              const float* __restrict__ bv,
              unsigned short* __restrict__ Qo, unsigned short* __restrict__ Ko,
              unsigned short* __restrict__ Vo) {
  GEMM_PROLOGUE()
  const int nseg = n0 >> 10;
  const float* bias = (nseg == 0) ? bq : ((nseg == 1) ? bk : bv);
#pragma unroll
  for (int rt = 0; rt < 4; ++rt) {
#pragma unroll
    for (int ct = 0; ct < 4; ++ct) {
      int mg = m0 + wm * 64 + rt * 16 + quad * 4;
      int ng = n0 + wn * 64 + ct * 16 + col;
      int c = ng & 1023;
      int hh = c >> 6, hd = c & 63;
      int b_ = mg >> 11, s = mg & 2047;
      float bb = bias[c];
      if (nseg == 2) {
        uintx2 pk;
        pk[0] = pk2(acc[rt][ct][0] + bb, acc[rt][ct][1] + bb);
        pk[1] = pk2(acc[rt][ct][2] + bb, acc[rt][ct][3] + bb);
        *(uintx2*)&Vo[(size_t)(b_ * 16 + hh) * 131072 + (size_t)hd * 2048 + s] = pk;
      } else {
        unsigned short* dst =
            ((nseg == 0) ? Qo : Ko) + ((size_t)(b_ * 16 + hh) * 2048 + s) * 64 + hd;
        // Q scale folds 1/sqrt(64) AND log2(e) (exp2-domain softmax downstream)
        float scl = (nseg == 0) ? (0.125f * LOG2E) : 1.0f;
#pragma unroll
        for (int i = 0; i < 4; ++i) dst[(size_t)i * 64] = f2bf((acc[rt][ct][i] + bb) * scl);
      }
    }
  }
}

__global__ __launch_bounds__(256, 3)
void gemm_out(const unsigned short* __restrict__ A, const unsigned short* __restrict__ Bt,
              const float* __restrict__ bo, float* __restrict__ Out) {
  GEMM_PROLOGUE()
#pragma unroll
  for (int rt = 0; rt < 4; ++rt) {
#pragma unroll
    for (int ct = 0; ct < 4; ++ct) {
      int mg = m0 + wm * 64 + rt * 16 + quad * 4;
      int ng = n0 + wn * 64 + ct * 16 + col;
      float bb = bo[ng];
#pragma unroll
      for (int i = 0; i < 4; ++i)
        Out[(size_t)(mg + i) * 1024 + ng] = acc[rt][ct][i] + bb;
    }
  }
}

// ---------------- flash attention v12 = v11 + reg-prefetch K/V (T14) + mask-skip + defer-max (T13)
// Q-tile 64 (4 waves x 16 q rows), kv-tile 128. K/V staged global->reg->LDS with
// next-tile prefetch issued under current compute (removes vmcnt(0) drain from the
// critical path). Per-kv-tile mask flags scanned once per block; mask bias math runs
// only on tiles that actually contain masked positions. Defer-max skips O-rescale
// when the tile max grows by <= 8 (exp2 domain, P <= 2^8, bf16-safe).
__global__ __launch_bounds__(256, 3)
void flash_attn(const unsigned short* __restrict__ Q, const unsigned short* __restrict__ K,
                const unsigned short* __restrict__ Vt, const float* __restrict__ mask,
                unsigned short* __restrict__ O) {
  __shared__ __align__(16) unsigned short Ks[128 * 64];   // [kv][hd c8], chunk^(r&7)
  __shared__ __align__(16) unsigned short Vs[64 * 128];   // [hd][kv c16], chunk^(r&15)
  __shared__ __align__(16) unsigned short Ps[64 * 128];   // P [q][c16] swizzled; Q stage [64][64]
  __shared__ int mflag[16];                               // per-kv-tile "has masked" flags

  const int tid = threadIdx.x;
  const int lane = tid & 63;
  const int wid = tid >> 6;
  const int col = lane & 15;
  const int quad = lane >> 4;
  const int j = 31 - (int)(blockIdx.x >> 5);  // q-tile (64 rows), longest first
  const int bh = blockIdx.x & 31;
  const int b = bh >> 4, h = bh & 15;
  const int q0 = j * 64;
  const int tdiag = j >> 1;                   // diagonal kv-tile (128 wide)

  const unsigned short* Qp = Q + (size_t)bh * 2048 * 64;
  const unsigned short* Kp = K + (size_t)bh * 2048 * 64;
  const unsigned short* Vp = Vt + (size_t)bh * 64 * 2048;
  const float* mp = mask + b * 2048;

  const int lr8 = lane >> 3, lc8 = lane & 7;    // Q staging lane coords
  const floatx4 fzero = (floatx4)(0.f);
  const floatx4 fone = (floatx4)(1.f);

  // K/V register-staging coords: K [128][64] 2 threads/row, V^T [64][128] 4 threads/row
  const int kr = tid >> 1, kh = (tid & 1) * 4;
  const int vr = tid >> 2, vh = (tid & 3) * 4;
  const unsigned short* Kg = Kp + (size_t)kr * 64 + kh * 8;
  const unsigned short* Vg = Vp + (size_t)vr * 2048 + vh * 8;
  unsigned short* Kl = Ks + kr * 64;
  unsigned short* Vl = Vs + vr * 128;

  // stage Q rows [64][64] into Ps (swizzled): LDS[r][c] = Q[r][c ^ (r&7)]
#pragma unroll
  for (int i = 0; i < 2; ++i) {
    int seg = wid * 2 + i;
    int r = seg * 8 + lr8;
    gload_lds16(Qp + (size_t)(q0 + r) * 64 + ((lc8 ^ (r & 7)) * 8), Ps + seg * 512);
  }
  if (tid < 16) mflag[tid] = 0;
  // prefetch K/V tile 0 into registers (linear global reads; swizzle applied on ds_write)
  short8 kreg[4], vreg[4];
#pragma unroll
  for (int c = 0; c < 4; ++c) kreg[c] = *(const short8*)(Kg + c * 8);
#pragma unroll
  for (int c = 0; c < 4; ++c) vreg[c] = *(const short8*)(Vg + c * 8);
  __syncthreads();  // staged Q + mflag init visible
  short8 qf[2];
  {
    int q = wid * 16 + col;
#pragma unroll
    for (int ks = 0; ks < 2; ++ks)
      qf[ks] = *(const short8*)&Ps[q * 64 + (((ks * 4 + quad) ^ (q & 7)) * 8)];
  }
  // one-time mask scan -> per-128-kv-tile flags (covers kv [0, (tdiag+1)*128))
  for (int c = tid; c < (tdiag + 1) * 32; c += 256) {
    floatx4 mm = *(const floatx4*)&mp[c * 4];
    if (mm[0] != 1.f || mm[1] != 1.f || mm[2] != 1.f || mm[3] != 1.f)
      atomicOr(&mflag[c >> 5], 1);
  }
  __syncthreads();  // flags ready; all waves' qf reads done (first P write safe)

  floatx4 o[4];
#pragma unroll
  for (int dt = 0; dt < 4; ++dt) o[dt] = fzero;
  float mrow = -1e30f;
  float lrow = 0.f;

#pragma unroll 1
  for (int t = 0; t <= tdiag; ++t) {
    if (t > 0) __syncthreads();  // prior iter's Ks/Vs frag reads done
    // LDS <- registers (swizzled ds_write_b128; 8-access/bank = conflict-free)
#pragma unroll
    for (int c = 0; c < 4; ++c) *(short8*)(Kl + (((kh + c) ^ (kr & 7)) * 8)) = kreg[c];
#pragma unroll
    for (int c = 0; c < 4; ++c) *(short8*)(Vl + (((vh + c) ^ (vr & 15)) * 8)) = vreg[c];
    // issue next tile's global loads: latency hides under this tile's compute
    if (t < tdiag) {
#pragma unroll
      for (int c = 0; c < 4; ++c)
        kreg[c] = *(const short8*)(Kg + (size_t)(t + 1) * 8192 + c * 8);
#pragma unroll
      for (int c = 0; c < 4; ++c)
        vreg[c] = *(const short8*)(Vg + (t + 1) * 128 + c * 8);
    }
    __syncthreads();  // staging visible

    // S^T: [kv=128][q=16 per wave]  (scores already x log2e via Q scale)
    floatx4 sc[8];
#pragma unroll
    for (int rt = 0; rt < 8; ++rt) {
      int krr = rt * 16 + col;
      short8 kf0 = *(const short8*)&Ks[krr * 64 + ((quad ^ (col & 7)) * 8)];
      short8 kf1 = *(const short8*)&Ks[krr * 64 + (((4 + quad) ^ (col & 7)) * 8)];
      floatx4 s0 = MFMA16(kf0, qf[0], fzero);
      sc[rt] = MFMA16(kf1, qf[1], s0);
    }
    // padding-mask additive bias only when this kv tile actually has masked cols
    if (__builtin_amdgcn_readfirstlane(mflag[t])) {
#pragma unroll
      for (int rt = 0; rt < 8; ++rt) {
        floatx4 mm = *(const floatx4*)&mp[t * 128 + rt * 16 + quad * 4];
        sc[rt] += (fone - mm) * (-1.0e9f * LOG2E);
      }
    }
    if (t == tdiag) {  // causal diagonal: -1e9 * log2e (exp2 domain)
      int qg = q0 + wid * 16 + col;
#pragma unroll
      for (int rt = 0; rt < 8; ++rt)
#pragma unroll
        for (int i = 0; i < 4; ++i)
          if (t * 128 + rt * 16 + quad * 4 + i > qg) sc[rt][i] = -1.0e9f * LOG2E;
    }

    // online softmax, exp2 domain (per-lane q row stats; 2 shuffles per reduce)
    float mt = -1e30f;
#pragma unroll
    for (int rt = 0; rt < 8; ++rt)
      mt = fmaxf(mt, fmaxf(fmaxf(sc[rt][0], sc[rt][1]), fmaxf(sc[rt][2], sc[rt][3])));
    mt = fmaxf(mt, __shfl_xor(mt, 16));
    mt = fmaxf(mt, __shfl_xor(mt, 32));

    // defer-max (T13): keep old max when tile max grew by <= 8 => P bounded by 2^8
    const bool skip = (__all(mt - mrow <= 8.0f) != 0);  // wave-uniform
    float mn = mrow;
    if (!skip) {
      mn = fmaxf(mrow, mt);
      float alpha = EXP2(mrow - mn);
      mrow = mn;
      lrow *= alpha;
#pragma unroll
      for (int dt = 0; dt < 4; ++dt) o[dt] *= alpha;
    }
    float sum = 0.f;
#pragma unroll
    for (int rt = 0; rt < 8; ++rt)
#pragma unroll
      for (int i = 0; i < 4; ++i) {
        float p = EXP2(sc[rt][i] - mn);
        sc[rt][i] = p;
        sum += p;
      }
    sum += __shfl_xor(sum, 16);
    sum += __shfl_xor(sum, 32);
    lrow += sum;
    // write P rows (own wave) swizzled: 8B at chunk (rt*2 + quad>>1) ^ col, half quad&1
    {
      int qloc = wid * 16 + col;
#pragma unroll
      for (int rt = 0; rt < 8; ++rt) {
        uintx2 w;
        w[0] = pk2(sc[rt][0], sc[rt][1]);
        w[1] = pk2(sc[rt][2], sc[rt][3]);
        int chunk = (rt * 2 + (quad >> 1)) ^ col;
        *(uintx2*)&Ps[qloc * 128 + chunk * 8 + (quad & 1) * 4] = w;
      }
    }
    // PV: O^T[d][q] += V^T * P^T (own-wave P rows; DS in-order per wave, no barrier)
#pragma unroll
    for (int ks = 0; ks < 4; ++ks) {
      int ch = ks * 4 + quad;
      short8 pf = *(const short8*)&Ps[(wid * 16 + col) * 128 + ((ch ^ col) * 8)];
#pragma unroll
      for (int dt = 0; dt < 4; ++dt) {
        short8 vf = *(const short8*)&Vs[(dt * 16 + col) * 128 + ((ch ^ col) * 8)];
        o[dt] = MFMA16(vf, pf, o[dt]);
      }
    }
  }

  // epilogue: O^T regs: d = dt*16 + quad*4 + i, q = wid*16 + col
  {
    float inv = 1.0f / lrow;
    int qg = q0 + wid * 16 + col;
    unsigned short* dst = O + ((size_t)(b * 2048 + qg)) * 1024 + h * 64;
#pragma unroll
    for (int dt = 0; dt < 4; ++dt) {
      uintx2 pk;
      pk[0] = pk2(o[dt][0] * inv, o[dt][1] * inv);
      pk[1] = pk2(o[dt][2] * inv, o[dt][3] * inv);
      *(uintx2*)&dst[dt * 16 + quad * 4] = pk;
    }
  }
}

// ---------------- launch ----------------
extern "C" void kernel_launch(void* const* d_in, const int* in_sizes, int n_in,
                              void* d_out, int out_size, void* d_ws, size_t ws_size,
                              hipStream_t stream) {
  (void)in_sizes; (void)n_in; (void)out_size; (void)ws_size;
  const float* x  = (const float*)d_in[0];
  const float* mask = (const float*)d_in[1];
  const float* Wq = (const float*)d_in[2];
  const float* bq = (const float*)d_in[3];
  const float* Wk = (const float*)d_in[4];
  const float* bk = (const float*)d_in[5];
  const float* Wv = (const float*)d_in[6];
  const float* bv = (const float*)d_in[7];
  const float* Wo = (const float*)d_in[8];
  const float* bo = (const float*)d_in[9];
  float* out = (float*)d_out;

  char* ws = (char*)d_ws;
  unsigned short* xb    = (unsigned short*)(ws);                    // 8 MB
  unsigned short* Wqkvt = (unsigned short*)(ws + (8u << 20));       // 6 MB
  unsigned short* Wot   = (unsigned short*)(ws + (14u << 20));      // 2 MB
  unsigned short* Qb    = (unsigned short*)(ws + (16u << 20));      // 8 MB
  unsigned short* Kb    = (unsigned short*)(ws + (24u << 20));      // 8 MB
  unsigned short* Vtb   = (unsigned short*)(ws + (32u << 20));      // 8 MB
  unsigned short* Ao    = (unsigned short*)(ws + (40u << 20));      // 8 MB (48 MB total)

  convert_x<<<4096, 256, 0, stream>>>(x, xb);
  transpose_w<<<dim3(32, 32, 4), dim3(32, 8), 0, stream>>>(Wq, Wk, Wv, Wo, Wqkvt, Wot);
  gemm_qkv<<<dim3(32, 24), 256, 0, stream>>>(xb, Wqkvt, bq, bk, bv, Qb, Kb, Vtb);
  flash_attn<<<dim3(1024), 256, 0, stream>>>(Qb, Kb, Vtb, mask, Ao);
  gemm_out<<<dim3(32, 8), 256, 0, stream>>>(Ao, Wot, bo, out);
}

// Round 4
// 183.618 us; speedup vs baseline: 1.0133x; 1.0133x over previous
//
#include <hip/hip_runtime.h>
#include <hip/hip_bf16.h>
#include <cstdint>
#include <cstddef>

// ---- types ----
typedef __attribute__((ext_vector_type(8))) short short8;       // 8 bf16 (4 VGPR) MFMA frag
typedef __attribute__((ext_vector_type(4))) float floatx4;      // MFMA accumulator
typedef __attribute__((ext_vector_type(2))) unsigned int uintx2;     // 8B vector st

#define MFMA16(a, b, c) __builtin_amdgcn_mfma_f32_16x16x32_bf16((a), (b), (c), 0, 0, 0)
#define LOG2E 1.44269504088896340736f
#define EXP2(x) __builtin_amdgcn_exp2f(x)

__device__ __forceinline__ unsigned short f2bf(float f) {
  unsigned int u = __builtin_bit_cast(unsigned int, f);
  u += 0x7fffu + ((u >> 16) & 1u);          // RNE
  return (unsigned short)(u >> 16);
}

// packed bf16 pair via v_cvt_pk_bf16_f32 (RNE); memcpy avoids bit_cast restriction
__device__ __forceinline__ unsigned int pk2(float a, float b) {
  float2 f; f.x = a; f.y = b;
  __hip_bfloat162 h = __float22bfloat162_rn(f);
  unsigned int u;
  __builtin_memcpy(&u, &h, 4);
  return u;
}

typedef __attribute__((address_space(1))) void gvoid_t;
typedef __attribute__((address_space(3))) void svoid_t;
__device__ __forceinline__ void gload_lds16(const void* g, void* l) {
  // LDS dest = wave-uniform base + lane*16; global side is per-lane addresses.
  __builtin_amdgcn_global_load_lds((gvoid_t*)(uintptr_t)g, (svoid_t*)(uintptr_t)l, 16, 0, 0);
}

// ---------------- convert x: fp32 -> bf16 ----------------
__global__ void convert_x(const float* __restrict__ x, unsigned short* __restrict__ xb) {
  int i = (blockIdx.x * 256 + threadIdx.x) * 4;
  floatx4 v = *(const floatx4*)(x + i);
  uintx2 o;
  o[0] = pk2(v[0], v[1]);
  o[1] = pk2(v[2], v[3]);
  *(uintx2*)(xb + i) = o;
}

// ---------------- transpose weights -> bf16 N x K ----------------
__global__ void transpose_w(const float* __restrict__ Wq, const float* __restrict__ Wk,
                            const float* __restrict__ Wv, const float* __restrict__ Wo,
                            unsigned short* __restrict__ Wqkvt, unsigned short* __restrict__ Wot) {
  __shared__ float tile[32][33];
  int z = blockIdx.z;
  const float* W = (z == 0) ? Wq : (z == 1) ? Wk : (z == 2) ? Wv : Wo;
  unsigned short* out = (z == 3) ? Wot : (Wqkvt + (size_t)z * 1024 * 1024);
  int n0 = blockIdx.x * 32, k0 = blockIdx.y * 32;
  int tx = threadIdx.x, ty = threadIdx.y;            // block (32,8)
#pragma unroll
  for (int j = 0; j < 4; ++j)
    tile[ty + j * 8][tx] = W[(size_t)(k0 + ty + j * 8) * 1024 + n0 + tx];
  __syncthreads();
#pragma unroll
  for (int j = 0; j < 4; ++j)
    out[(size_t)(n0 + ty + j * 8) * 1024 + k0 + tx] = f2bf(tile[tx][ty + j * 8]);
}

// ---------------- GEMM core v4: 128x128 tile (m97 shape), BK=64, XOR-swizzled LDS ----------------
// 4 waves, each owns a 64x64 quadrant (acc[4][4] of 16x16). 32 KB LDS, 2-barrier loop.
#define GEMM_PROLOGUE()                                                        \
  __shared__ __align__(16) unsigned short As[128 * 64];                        \
  __shared__ __align__(16) unsigned short Bs[128 * 64];                        \
  const int tid = threadIdx.x;                                                 \
  const int lane = tid & 63;                                                   \
  const int wid = tid >> 6;                                                    \
  const int col = lane & 15;                                                   \
  const int quad = lane >> 4;                                                  \
  const int m0 = blockIdx.x * 128;                                             \
  const int n0 = blockIdx.y * 128;                                             \
  const int wm = wid >> 1;                                                     \
  const int wn = wid & 1;                                                      \
  floatx4 acc[4][4];                                                           \
  _Pragma("unroll") for (int i = 0; i < 4; ++i)                                \
      _Pragma("unroll") for (int j = 0; j < 4; ++j)                            \
          acc[i][j] = (floatx4)(0.f);                                          \
  _Pragma("unroll 1") for (int kt = 0; kt < 16; ++kt) {                        \
    __syncthreads();                                                           \
    _Pragma("unroll") for (int call = 0; call < 4; ++call) {                   \
      int c = call * 256 + tid;                                                \
      int r = c >> 3, ch = c & 7;                                              \
      gload_lds16(A + (size_t)(m0 + r) * 1024 + kt * 64 + ((ch ^ (r & 7)) * 8),\
                  As + (size_t)(call * 256 + wid * 64) * 8);                   \
      gload_lds16(Bt + (size_t)(n0 + r) * 1024 + kt * 64 + ((ch ^ (r & 7)) * 8),\
                  Bs + (size_t)(call * 256 + wid * 64) * 8);                   \
    }                                                                          \
    __syncthreads();                                                           \
    _Pragma("unroll") for (int ks = 0; ks < 2; ++ks) {                         \
      short8 af[4], bf[4];                                                     \
      _Pragma("unroll") for (int rt = 0; rt < 4; ++rt) {                       \
        int row = wm * 64 + rt * 16 + col;                                     \
        af[rt] = *(const short8*)&As[row * 64 + (((ks * 4 + quad) ^ (row & 7)) * 8)]; \
      }                                                                        \
      _Pragma("unroll") for (int ct = 0; ct < 4; ++ct) {                       \
        int row = wn * 64 + ct * 16 + col;                                     \
        bf[ct] = *(const short8*)&Bs[row * 64 + (((ks * 4 + quad) ^ (row & 7)) * 8)]; \
      }                                                                        \
      _Pragma("unroll") for (int rt = 0; rt < 4; ++rt)                         \
          _Pragma("unroll") for (int ct = 0; ct < 4; ++ct)                     \
              acc[rt][ct] = MFMA16(af[rt], bf[ct], acc[rt][ct]);               \
    }                                                                          \
  }

__global__ __launch_bounds__(256, 3)
void gemm_qkv(const unsigned short* __restrict__ A, const unsigned short* __restrict__ Bt,
              const float* __restrict__ bq, const float* __restrict__ bk,
              const float* __restrict__ bv,
              unsigned short* __restrict__ Qo, unsigned short* __restrict__ Ko,
              unsigned short* __restrict__ Vo) {
  GEMM_PROLOGUE()
  const int nseg = n0 >> 10;
  const float* bias = (nseg == 0) ? bq : ((nseg == 1) ? bk : bv);
#pragma unroll
  for (int rt = 0; rt < 4; ++rt) {
#pragma unroll
    for (int ct = 0; ct < 4; ++ct) {
      int mg = m0 + wm * 64 + rt * 16 + quad * 4;
      int ng = n0 + wn * 64 + ct * 16 + col;
      int c = ng & 1023;
      int hh = c >> 6, hd = c & 63;
      int b_ = mg >> 11, s = mg & 2047;
      float bb = bias[c];
      if (nseg == 2) {
        uintx2 pk;
        pk[0] = pk2(acc[rt][ct][0] + bb, acc[rt][ct][1] + bb);
        pk[1] = pk2(acc[rt][ct][2] + bb, acc[rt][ct][3] + bb);
        *(uintx2*)&Vo[(size_t)(b_ * 16 + hh) * 131072 + (size_t)hd * 2048 + s] = pk;
      } else {
        unsigned short* dst =
            ((nseg == 0) ? Qo : Ko) + ((size_t)(b_ * 16 + hh) * 2048 + s) * 64 + hd;
        // Q scale folds 1/sqrt(64) AND log2(e) (exp2-domain softmax downstream)
        float scl = (nseg == 0) ? (0.125f * LOG2E) : 1.0f;
#pragma unroll
        for (int i = 0; i < 4; ++i) dst[(size_t)i * 64] = f2bf((acc[rt][ct][i] + bb) * scl);
      }
    }
  }
}

__global__ __launch_bounds__(256, 3)
void gemm_out(const unsigned short* __restrict__ A, const unsigned short* __restrict__ Bt,
              const float* __restrict__ bo, float* __restrict__ Out) {
  GEMM_PROLOGUE()
#pragma unroll
  for (int rt = 0; rt < 4; ++rt) {
#pragma unroll
    for (int ct = 0; ct < 4; ++ct) {
      int mg = m0 + wm * 64 + rt * 16 + quad * 4;
      int ng = n0 + wn * 64 + ct * 16 + col;
      float bb = bo[ng];
#pragma unroll
      for (int i = 0; i < 4; ++i)
        Out[(size_t)(mg + i) * 1024 + ng] = acc[rt][ct][i] + bb;
    }
  }
}

// ---------------- flash attention v14: P-in-Ks, 32 KB LDS, 4 blocks/CU ----------------
// v11's proven structure (gload_lds K/V staging, P LDS round-trip, own-wave P rows)
// + mask-skip ballot + defer-max + setprio. The 16 KB P buffer is folded into Ks:
// after the QK^T MFMA cluster the K-fragments are dead, so one extra barrier makes
// Ks reusable as the P buffer. LDS = exactly 32 KB -> 4 blocks/CU, grid 1024 fully
// resident. Balanced slot mapping equalizes per-CU tile-iteration totals.
__global__ __launch_bounds__(256, 4)
void flash_attn(const unsigned short* __restrict__ Q, const unsigned short* __restrict__ K,
                const unsigned short* __restrict__ Vt, const float* __restrict__ mask,
                unsigned short* __restrict__ O) {
  __shared__ __align__(16) unsigned short Ks[128 * 64];   // K [kv][hd c8] chunk^(r&7); then P [q][c16]
  __shared__ __align__(16) unsigned short Vs[64 * 128];   // [hd][kv c16], chunk^(r&15)

  const int tid = threadIdx.x;
  const int lane = tid & 63;
  const int wid = tid >> 6;
  const int col = lane & 15;
  const int quad = lane >> 4;
  // balanced mapping: slot j-ranges {24..31, 0..7, 16..23, 8..15}; with round-robin
  // dispatch a CU's 4 resident blocks sum to ~30 tile-iterations regardless of h8.
  const int slot = (int)(blockIdx.x >> 8);
  const int g = (int)(blockIdx.x & 255);
  const int h8 = g >> 5;
  const int bh = g & 31;
  const int j = (slot == 0) ? (31 - h8) : (slot == 1) ? h8 : (slot == 2) ? (23 - h8) : (8 + h8);
  const int b = bh >> 4, h = bh & 15;
  const int q0 = j * 64;
  const int tdiag = j >> 1;                   // diagonal kv-tile (128 wide)

  const unsigned short* Qp = Q + (size_t)bh * 2048 * 64;
  const unsigned short* Kp = K + (size_t)bh * 2048 * 64;
  const unsigned short* Vp = Vt + (size_t)bh * 64 * 2048;
  const float* mp = mask + b * 2048;

  const int lr8 = lane >> 3, lc8 = lane & 7;    // K/Q staging lane coords
  const int lr16 = lane >> 4, lc16 = lane & 15; // V staging lane coords
  const floatx4 fzero = (floatx4)(0.f);
  const floatx4 fone = (floatx4)(1.f);

  // stage Q rows [64][64] into Ks (swizzled): LDS[r][c] = Q[r][c ^ (r&7)]
#pragma unroll
  for (int i = 0; i < 2; ++i) {
    int seg = wid * 2 + i;
    int r = seg * 8 + lr8;
    gload_lds16(Qp + (size_t)(q0 + r) * 64 + ((lc8 ^ (r & 7)) * 8), Ks + seg * 512);
  }
  __syncthreads();  // staged Q visible
  short8 qf[2];
  {
    int q = wid * 16 + col;
#pragma unroll
    for (int ks = 0; ks < 2; ++ks)
      qf[ks] = *(const short8*)&Ks[q * 64 + (((ks * 4 + quad) ^ (q & 7)) * 8)];
  }
  // per-wave mask bitmask: bit t set iff kv-tile t contains any masked position
  unsigned int mbits = 0;
  for (int t = 0; t <= tdiag; ++t) {
    float2 mv = *(const float2*)&mp[t * 128 + lane * 2];
    unsigned long long bb = __ballot(mv.x != 1.f || mv.y != 1.f);
    mbits |= (bb ? 1u : 0u) << t;
  }

  floatx4 o[4];
#pragma unroll
  for (int dt = 0; dt < 4; ++dt) o[dt] = fzero;
  float mrow = -1e30f;
  float lrow = 0.f;

#pragma unroll 1
  for (int t = 0; t <= tdiag; ++t) {
    __syncthreads();  // prior iter's P/Vs reads (or prologue qf reads) done before restage
#pragma unroll
    for (int i = 0; i < 4; ++i) {  // K tile [128][64]
      int seg = wid * 4 + i;
      int r = seg * 8 + lr8;
      gload_lds16(Kp + (size_t)(t * 128 + r) * 64 + ((lc8 ^ (r & 7)) * 8), Ks + seg * 512);
    }
#pragma unroll
    for (int i = 0; i < 4; ++i) {  // V^T tile [64][128]
      int seg = wid * 4 + i;
      int r = seg * 4 + lr16;
      gload_lds16(Vp + (size_t)r * 2048 + t * 128 + ((lc16 ^ (r & 15)) * 8), Vs + seg * 512);
    }
    __syncthreads();  // staging visible

    // S^T: [kv=128][q=16 per wave]  (scores already x log2e via Q scale)
    floatx4 sc[8];
    __builtin_amdgcn_s_setprio(1);
#pragma unroll
    for (int rt = 0; rt < 8; ++rt) {
      int kr = rt * 16 + col;
      short8 kf0 = *(const short8*)&Ks[kr * 64 + ((quad ^ (col & 7)) * 8)];
      short8 kf1 = *(const short8*)&Ks[kr * 64 + (((4 + quad) ^ (col & 7)) * 8)];
      floatx4 s0 = MFMA16(kf0, qf[0], fzero);
      sc[rt] = MFMA16(kf1, qf[1], s0);
    }
    __builtin_amdgcn_s_setprio(0);
    __syncthreads();  // all waves' K-fragment reads done: Ks reusable as P buffer

    // padding-mask additive bias only on tiles that actually have masked cols
    if (__builtin_amdgcn_readfirstlane(mbits >> t) & 1) {
#pragma unroll
      for (int rt = 0; rt < 8; ++rt) {
        floatx4 mm = *(const floatx4*)&mp[t * 128 + rt * 16 + quad * 4];
        sc[rt] += (fone - mm) * (-1.0e9f * LOG2E);
      }
    }
    if (t == tdiag) {  // causal diagonal: -1e9 * log2e (exp2 domain)
      int qg = q0 + wid * 16 + col;
#pragma unroll
      for (int rt = 0; rt < 8; ++rt)
#pragma unroll
        for (int i = 0; i < 4; ++i)
          if (t * 128 + rt * 16 + quad * 4 + i > qg) sc[rt][i] = -1.0e9f * LOG2E;
    }

    // online softmax, exp2 domain (per-lane q row stats; 2 shuffles per reduce)
    float mt = -1e30f;
#pragma unroll
    for (int rt = 0; rt < 8; ++rt)
      mt = fmaxf(mt, fmaxf(fmaxf(sc[rt][0], sc[rt][1]), fmaxf(sc[rt][2], sc[rt][3])));
    mt = fmaxf(mt, __shfl_xor(mt, 16));
    mt = fmaxf(mt, __shfl_xor(mt, 32));

    // defer-max (T13): keep old max when tile max grew by <= 8 => P bounded by 2^8
    const bool skip = (__all(mt - mrow <= 8.0f) != 0);  // wave-uniform
    float mn = mrow;
    if (!skip) {
      mn = fmaxf(mrow, mt);
      float alpha = EXP2(mrow - mn);
      mrow = mn;
      lrow *= alpha;
#pragma unroll
      for (int dt = 0; dt < 4; ++dt) o[dt] *= alpha;
    }
    float sum = 0.f;
#pragma unroll
    for (int rt = 0; rt < 8; ++rt)
#pragma unroll
      for (int i = 0; i < 4; ++i) {
        float p = EXP2(sc[rt][i] - mn);
        sc[rt][i] = p;
        sum += p;
      }
    sum += __shfl_xor(sum, 16);
    sum += __shfl_xor(sum, 32);
    lrow += sum;

    // write P rows (own wave) into Ks, swizzled: 8B at chunk (rt*2 + quad>>1) ^ col
    {
      int qloc = wid * 16 + col;
#pragma unroll
      for (int rt = 0; rt < 8; ++rt) {
        uintx2 w;
        w[0] = pk2(sc[rt][0], sc[rt][1]);
        w[1] = pk2(sc[rt][2], sc[rt][3]);
        int chunk = (rt * 2 + (quad >> 1)) ^ col;
        *(uintx2*)&Ks[qloc * 128 + chunk * 8 + (quad & 1) * 4] = w;
      }
    }
    // PV: O^T[d][q] += V^T * P^T (own-wave P rows; DS in-order per wave, no barrier)
    __builtin_amdgcn_s_setprio(1);
#pragma unroll
    for (int ks = 0; ks < 4; ++ks) {
      int ch = ks * 4 + quad;
      short8 pf = *(const short8*)&Ks[(wid * 16 + col) * 128 + ((ch ^ col) * 8)];
#pragma unroll
      for (int dt = 0; dt < 4; ++dt) {
        short8 vf = *(const short8*)&Vs[(dt * 16 + col) * 128 + ((ch ^ col) * 8)];
        o[dt] = MFMA16(vf, pf, o[dt]);
      }
    }
    __builtin_amdgcn_s_setprio(0);
  }

  // epilogue: O^T regs: d = dt*16 + quad*4 + i, q = wid*16 + col
  {
    float inv = 1.0f / lrow;
    int qg = q0 + wid * 16 + col;
    unsigned short* dst = O + ((size_t)(b * 2048 + qg)) * 1024 + h * 64;
#pragma unroll
    for (int dt = 0; dt < 4; ++dt) {
      uintx2 pk;
      pk[0] = pk2(o[dt][0] * inv, o[dt][1] * inv);
      pk[1] = pk2(o[dt][2] * inv, o[dt][3] * inv);
      *(uintx2*)&dst[dt * 16 + quad * 4] = pk;
    }
  }
}

// ---------------- launch ----------------
extern "C" void kernel_launch(void* const* d_in, const int* in_sizes, int n_in,
                              void* d_out, int out_size, void* d_ws, size_t ws_size,
                              hipStream_t stream) {
  (void)in_sizes; (void)n_in; (void)out_size; (void)ws_size;
  const float* x  = (const float*)d_in[0];
  const float* mask = (const float*)d_in[1];
  const float* Wq = (const float*)d_in[2];
  const float* bq = (const float*)d_in[3];
  const float* Wk = (const float*)d_in[4];
  const float* bk = (const float*)d_in[5];
  const float* Wv = (const float*)d_in[6];
  const float* bv = (const float*)d_in[7];
  const float* Wo = (const float*)d_in[8];
  const float* bo = (const float*)d_in[9];
  float* out = (float*)d_out;

  char* ws = (char*)d_ws;
  unsigned short* xb    = (unsigned short*)(ws);                    // 8 MB
  unsigned short* Wqkvt = (unsigned short*)(ws + (8u << 20));       // 6 MB
  unsigned short* Wot   = (unsigned short*)(ws + (14u << 20));      // 2 MB
  unsigned short* Qb    = (unsigned short*)(ws + (16u << 20));      // 8 MB
  unsigned short* Kb    = (unsigned short*)(ws + (24u << 20));      // 8 MB
  unsigned short* Vtb   = (unsigned short*)(ws + (32u << 20));      // 8 MB
  unsigned short* Ao    = (unsigned short*)(ws + (40u << 20));      // 8 MB (48 MB total)

  convert_x<<<4096, 256, 0, stream>>>(x, xb);
  transpose_w<<<dim3(32, 32, 4), dim3(32, 8), 0, stream>>>(Wq, Wk, Wv, Wo, Wqkvt, Wot);
  gemm_qkv<<<dim3(32, 24), 256, 0, stream>>>(xb, Wqkvt, bq, bk, bv, Qb, Kb, Vtb);
  flash_attn<<<dim3(1024), 256, 0, stream>>>(Qb, Kb, Vtb, mask, Ao);
  gemm_out<<<dim3(32, 8), 256, 0, stream>>>(Ao, Wot, bo, out);
}